// Round 16
// baseline (240.288 us; speedup 1.0000x reference)
//
#include <hip/hip_runtime.h>

// ---------------------------------------------------------------------------
// QuaternionLinear == one dense GEMM: out[M,N] = x[M,K] @ W_eff[N,K]^T + bias
//   M = 16384 (B*S), N = 2048 (OUT_F), K = 2048 (IN_F)
// Pipeline: prep (fp32->bf16 x + build W_eff) ; qgemm.
// R16 = R13 schedule (one-phase operand lookahead, A 2-ring + B 3-ring
// 160KB, ONE end-of-tile lgkm(0)+vmcnt(4)+barrier, literal rings, XCD
// swizzle, no setprio) + mfma_f32_32x32x16_bf16 + COLUMN-MAJOR-BY-CHUNK LDS:
// physical 16B-chunk p = c*256 + r. A 32x32 frag read (32 consecutive rows,
// fixed k-chunk c) is then 512B CONTIGUOUS -> conflict-free (R11's row-major
// 32-row pattern was a pigeonhole 4-way conflict, 1.26e7 counts). Staging
// keeps linear LDS dest (global_load_lds) with per-lane source (r,c) math.
// 32x32 shaves the MFMA-pipe term ~17% (2495 vs 2075 TF ubench) at equal
// LDS traffic (24 b128/wave/tile both shapes).
// Lessons kept: R12 (B prefetch distance), R9 (no divergence around acc),
// R6 (literal rings), R14 (no instr interleave), R15 (no setprio).
// ---------------------------------------------------------------------------

typedef unsigned short u16;
typedef __bf16 bf16x8 __attribute__((ext_vector_type(8)));
typedef float f32x16 __attribute__((ext_vector_type(16)));

#define QM 16384
#define QN 2048
#define QK 2048

__device__ __forceinline__ u16 f2bf(float f) {
    union { float f; unsigned u; } v;
    v.f = f;
    unsigned r = v.u + 0x7FFFu + ((v.u >> 16) & 1u);
    return (u16)(r >> 16);
}

__device__ __forceinline__ void async_copy16(const u16* g, u16* l) {
    __builtin_amdgcn_global_load_lds(
        (const __attribute__((address_space(1))) void*)g,
        (__attribute__((address_space(3))) void*)l,
        16, 0, 0);
}

// ---------------------------------------------------------------------------
// prep: blocks [0,4096) convert x fp32->bf16; blocks [4096,8192) build W_eff.
// ---------------------------------------------------------------------------
__global__ void prep_kernel(const float* __restrict__ x, u16* __restrict__ xb,
                            const float* __restrict__ wr, const float* __restrict__ wi,
                            const float* __restrict__ wj, const float* __restrict__ wk,
                            u16* __restrict__ wb) {
    const int b = blockIdx.x;
    if (b < 4096) {
        const int n4 = (QM * QK) / 4;
        for (int i = b * blockDim.x + threadIdx.x; i < n4; i += 4096 * blockDim.x) {
            float4 v = reinterpret_cast<const float4*>(x)[i];
            ushort4 o;
            o.x = f2bf(v.x); o.y = f2bf(v.y); o.z = f2bf(v.z); o.w = f2bf(v.w);
            reinterpret_cast<ushort4*>(xb)[i] = o;
        }
    } else {
        int i = (b - 4096) * blockDim.x + threadIdx.x;   // [0, QN*QK/4)
        int n = i >> 9;
        int p = i & 511;
        int q = n >> 2, co = n & 3;
        int base = (q << 9) + p;
        float r  = wr[base], ii = wi[base], jj = wj[base], kk = wk[base];
        float e0, e1, e2, e3;
        if      (co == 0) { e0 = r;  e1 = -ii; e2 = -jj; e3 = -kk; }
        else if (co == 1) { e0 = ii; e1 = r;   e2 = -jj; e3 = kk;  }
        else if (co == 2) { e0 = jj; e1 = ii;  e2 = r;   e3 = -kk; }
        else              { e0 = kk; e1 = -ii; e2 = jj;  e3 = r;   }
        ushort4 o;
        o.x = f2bf(e0); o.y = f2bf(e1); o.z = f2bf(e2); o.w = f2bf(e3);
        reinterpret_cast<ushort4*>(wb)[(n << 9) + p] = o;
    }
}

// ---------------------------------------------------------------------------
// LDS (u16): A bufs [0,32768) = 2 x 16384; B bufs [32768,81920) = 3 x 16384.
// Buffer = 2048 chunks of 16B, COLUMN-MAJOR: physical chunk p = c*256 + r
// (c = k-chunk 0..7 within BK=64, r = row 0..255). Elem addr = p*8.
// Per K-tile t (4 phases = K-steps s=0..3):
//   ph0: stage A(t+1) col-half0; read s=1 frags; MFMA s=0 (carried aS0/bS0)
//   ph1: stage A(t+1) col-half1; read s=2 frags; MFMA s=1
//   ph2: stage B(t+2) col-half0; read s=3 frags; MFMA s=2
//   ph3: stage B(t+2) col-half1; END lgkm(0)+vmcnt(4)+barrier;
//        pre-read s=0 of tile t+1; MFMA s=3
// Race proof (= R13): [1] A(t+1) dest buf^1: tile-(t-1) readers drained at
// t-1's END lgkm(0); residency via END vmcnt(4). [2] B(t+2) dest (t+2)%3
// disjoint from t%3 and (t+1)%3; buf t%3 next written at t+1, after my
// reads drained. [3] END queue [B(t+1)x4, A(t+1)x4, B(t+2)x4]; vmcnt(4) =>
// tile t+1 resident. [4] post-barrier pre-read targets resident bufs whose
// next writers run after t+1's END barrier.
// ---------------------------------------------------------------------------
__global__ __launch_bounds__(512, 2) void qgemm_kernel(const u16* __restrict__ A,
                                                       const u16* __restrict__ B,
                                                       const float* __restrict__ bias,
                                                       float* __restrict__ C) {
    __shared__ __align__(16) u16 L[81920];      // 160 KB

    const int bid = blockIdx.x;                 // 512 blocks, %8==0
    const int swz = (bid & 7) * 64 + (bid >> 3);
    const int bm = swz >> 3;                    // 0..63
    const int bn = swz & 7;                     // 0..7

    const int tid = threadIdx.x;
    const int wid = tid >> 6, lane = tid & 63;
    const int wm = wid >> 2, wn = wid & 3;
    const int lr = lane & 31;                   // row-in-frag
    const int hi = lane >> 5;                   // k-half

    const u16* Asrc = A + (size_t)bm * 256 * QK;
    const u16* Bsrc = B + (size_t)bn * 256 * QK;

    // staging geometry (column-major): thread covers physical chunks
    // {o*512 + tid} of a column-half; c = h*4 + o*2 + (tid>>8), r = tid&255.
    const int srow = tid & 255;
    const int scol0 = tid >> 8;                 // 0 or 1
    // LDS dest (elems): lbase + h*8192 + o*4096 + tid*8  (linear, lane*16B)

    f32x16 acc[4][2];
#pragma unroll
    for (int i = 0; i < 4; ++i)
#pragma unroll
        for (int j = 0; j < 2; ++j)
            acc[i][j] = (f32x16){0.f};

    // stage column-half h of a 256x64 tile at global k-offset k0
    auto stage = [&](const u16* src, int lbase, int k0, int h) {
#pragma unroll
        for (int o = 0; o < 2; ++o) {
            const int c = h * 4 + o * 2 + scol0;
            async_copy16(src + (size_t)srow * QK + k0 + c * 8,
                         &L[lbase + h * 8192 + o * 4096 + wid * 512]);
        }
    };

    // 32x32 frag reads: contiguous 512B per 32-lane group (conflict-free)
    auto rdA = [&](const u16* LA, int mt, int s) -> bf16x8 {
        const int r = wm * 128 + mt * 32 + lr;
        const int c = s * 2 + hi;
        return *(const bf16x8*)&LA[c * 2048 + r * 8];
    };
    auto rdB = [&](const u16* LB, int nt, int s) -> bf16x8 {
        const int r = wn * 64 + nt * 32 + lr;
        const int c = s * 2 + hi;
        return *(const bf16x8*)&LB[c * 2048 + r * 8];
    };

    // carried across tiles: current tile's s=0 operands
    bf16x8 a0[4], b0[2];

    // ab=t&1, bt=t%3, bt2=(t+2)%3, abn=(t+1)&1, btn=(t+1)%3 — all LITERAL.
    auto doTile = [&](const int ab, const int bt, const int bt2,
                      const int abn, const int btn, const int t,
                      const bool preRead) __attribute__((always_inline)) {
        const u16* LA  = &L[ab * 16384];
        const u16* LB  = &L[32768 + bt * 16384];
        const u16* LAn = &L[abn * 16384];
        const u16* LBn = &L[32768 + btn * 16384];
        const int tw1 = (t + 1) & 31, tw2 = (t + 2) & 31;
        const int oA = abn * 16384;               // A(t+1) dest
        const int oB = 32768 + bt2 * 16384;       // B(t+2) dest

        bf16x8 a1[4], b1[2], a2[4], b2[2], a3[4], b3[2];

        // ---- ph0: stage A(t+1)h0; read s=1; MFMA s=0 (carried) -----------
        stage(Asrc, oA, tw1 * 64, 0);
#pragma unroll
        for (int nt = 0; nt < 2; ++nt) b1[nt] = rdB(LB, nt, 1);
#pragma unroll
        for (int mt = 0; mt < 4; ++mt) a1[mt] = rdA(LA, mt, 1);
#pragma unroll
        for (int mt = 0; mt < 4; ++mt)
#pragma unroll
            for (int nt = 0; nt < 2; ++nt)
                acc[mt][nt] = __builtin_amdgcn_mfma_f32_32x32x16_bf16(a0[mt], b0[nt], acc[mt][nt], 0, 0, 0);

        // ---- ph1: stage A(t+1)h1; read s=2; MFMA s=1 ----------------------
        stage(Asrc, oA, tw1 * 64, 1);
#pragma unroll
        for (int nt = 0; nt < 2; ++nt) b2[nt] = rdB(LB, nt, 2);
#pragma unroll
        for (int mt = 0; mt < 4; ++mt) a2[mt] = rdA(LA, mt, 2);
#pragma unroll
        for (int mt = 0; mt < 4; ++mt)
#pragma unroll
            for (int nt = 0; nt < 2; ++nt)
                acc[mt][nt] = __builtin_amdgcn_mfma_f32_32x32x16_bf16(a1[mt], b1[nt], acc[mt][nt], 0, 0, 0);

        // ---- ph2: stage B(t+2)h0; read s=3; MFMA s=2 ----------------------
        stage(Bsrc, oB, tw2 * 64, 0);
#pragma unroll
        for (int nt = 0; nt < 2; ++nt) b3[nt] = rdB(LB, nt, 3);
#pragma unroll
        for (int mt = 0; mt < 4; ++mt) a3[mt] = rdA(LA, mt, 3);
#pragma unroll
        for (int mt = 0; mt < 4; ++mt)
#pragma unroll
            for (int nt = 0; nt < 2; ++nt)
                acc[mt][nt] = __builtin_amdgcn_mfma_f32_32x32x16_bf16(a2[mt], b2[nt], acc[mt][nt], 0, 0, 0);

        // ---- ph3: stage B(t+2)h1; END sync; pre-read s=0(t+1); MFMA s=3 ---
        stage(Bsrc, oB, tw2 * 64, 1);
        asm volatile("s_waitcnt lgkmcnt(0) vmcnt(4)" ::: "memory");
        __builtin_amdgcn_s_barrier();
        if (preRead) {
#pragma unroll
            for (int nt = 0; nt < 2; ++nt) b0[nt] = rdB(LBn, nt, 0);
#pragma unroll
            for (int mt = 0; mt < 4; ++mt) a0[mt] = rdA(LAn, mt, 0);
        }
#pragma unroll
        for (int mt = 0; mt < 4; ++mt)
#pragma unroll
            for (int nt = 0; nt < 2; ++nt)
                acc[mt][nt] = __builtin_amdgcn_mfma_f32_32x32x16_bf16(a3[mt], b3[nt], acc[mt][nt], 0, 0, 0);
    };

    // prologue: A(0)->Abuf0, B(0)->Bbuf0, B(1)->Bbuf1
    stage(Asrc, 0,     0, 0);
    stage(Asrc, 0,     0, 1);
    stage(Bsrc, 32768, 0, 0);
    stage(Bsrc, 32768, 0, 1);
    stage(Bsrc, 32768 + 16384, 64, 0);
    stage(Bsrc, 32768 + 16384, 64, 1);
    asm volatile("s_waitcnt vmcnt(4)" ::: "memory");   // A(0),B(0) resident
    __builtin_amdgcn_s_barrier();
    // read tile 0's s=0 operands
#pragma unroll
    for (int nt = 0; nt < 2; ++nt) b0[nt] = rdB(&L[32768], nt, 0);
#pragma unroll
    for (int mt = 0; mt < 4; ++mt) a0[mt] = rdA(&L[0], mt, 0);

    // 32 tiles = 5 x 6 (lcm of rings 2,3) + 2 tail; literal ring indices.
    //            ab bt bt2 abn btn  t
    for (int t = 0; t < 30; t += 6) {
        doTile(0, 0, 2, 1, 1, t,     true);
        doTile(1, 1, 0, 0, 2, t + 1, true);
        doTile(0, 2, 1, 1, 0, t + 2, true);
        doTile(1, 0, 2, 0, 1, t + 3, true);
        doTile(0, 1, 0, 1, 2, t + 4, true);
        doTile(1, 2, 1, 0, 0, t + 5, true);
    }
    doTile(0, 0, 2, 1, 1, 30, true);
    doTile(1, 1, 0, 0, 2, 31, false);   // last tile: no wrap pre-read

    // epilogue: 32x32 C/D layout col = lane&31, row = (e&3)+8*(e>>2)+4*hi
    const int colbase = bn * 256 + wn * 64;
    const int rowbase = bm * 256 + wm * 128;
    float bsv[2];
#pragma unroll
    for (int nt = 0; nt < 2; ++nt) bsv[nt] = bias[colbase + nt * 32 + lr];
    float* Cb = C + (size_t)rowbase * QN + colbase;
#pragma unroll
    for (int mt = 0; mt < 4; ++mt)
#pragma unroll
        for (int nt = 0; nt < 2; ++nt)
#pragma unroll
            for (int e = 0; e < 16; ++e) {
                const int ro = mt * 32 + (e & 3) + 8 * (e >> 2) + 4 * hi;
                Cb[(size_t)ro * QN + nt * 32 + lr] = acc[mt][nt][e] + bsv[nt];
            }
}

// ---------------------------------------------------------------------------
extern "C" void kernel_launch(void* const* d_in, const int* in_sizes, int n_in,
                              void* d_out, int out_size, void* d_ws, size_t ws_size,
                              hipStream_t stream) {
    const float* x    = (const float*)d_in[0];
    const float* wr   = (const float*)d_in[1];
    const float* wi   = (const float*)d_in[2];
    const float* wj   = (const float*)d_in[3];
    const float* wk   = (const float*)d_in[4];
    const float* bias = (const float*)d_in[5];
    float* out = (float*)d_out;

    u16* xb = (u16*)d_ws;                                   // 64 MB
    u16* wb = (u16*)((char*)d_ws + (size_t)QM * QK * 2);    // 8 MB

    prep_kernel<<<8192, 256, 0, stream>>>(x, xb, wr, wi, wj, wk, wb);
    qgemm_kernel<<<512, 512, 0, stream>>>(xb, wb, bias, out);
}

// Round 17
// 171.428 us; speedup vs baseline: 1.4017x; 1.4017x over previous
//
#include <hip/hip_runtime.h>

// ---------------------------------------------------------------------------
// QuaternionLinear == one dense GEMM: out[M,N] = x[M,K] @ W_eff[N,K]^T + bias
//   M = 16384 (B*S), N = 2048 (OUT_F), K = 2048 (IN_F)
// Pipeline: prep (fp32->bf16 x + build W_eff) ; qgemm.
// R17 = R13 schedule at 128x128 tile / 256 threads / 80KB LDS -> TWO blocks
// per CU. R13's residual (~1850 cyc/tile above the LDS floor) is the END
// barrier drain with 1 block/CU: all 8 waves wait together, CU idles.
// Two independent blocks have uncorrelated barriers -> block A's MFMA covers
// block B's drain. (R8 tested more waves in ONE block: shared barrier, no
// help. This is the untested inter-block mechanism.)
// Kept verbatim from R13: one-phase operand lookahead incl. post-barrier
// pre-read, A 2-ring + B 3-ring, stage positions (Ah0,Ah1,Bh0,Bh1), single
// END lgkm(0)+vmcnt(4)+barrier, chunk-XOR swizzle (0-conflict), literal
// ring indices, XCD swizzle, no setprio, 16x16x32 MFMA.
// Lessons: R16 (32x32+gload_lds incompatible: conflict-free LDS XOR
// coalesced HBM), R15 (no setprio), R14 (no instr interleave), R12 (keep B
// prefetch distance), R11 (16x16 frags), R9 (no divergence around acc).
// ---------------------------------------------------------------------------

typedef unsigned short u16;
typedef __bf16 bf16x8 __attribute__((ext_vector_type(8)));
typedef float f32x4 __attribute__((ext_vector_type(4)));

#define QM 16384
#define QN 2048
#define QK 2048

__device__ __forceinline__ u16 f2bf(float f) {
    union { float f; unsigned u; } v;
    v.f = f;
    unsigned r = v.u + 0x7FFFu + ((v.u >> 16) & 1u);
    return (u16)(r >> 16);
}

__device__ __forceinline__ void async_copy16(const u16* g, u16* l) {
    __builtin_amdgcn_global_load_lds(
        (const __attribute__((address_space(1))) void*)g,
        (__attribute__((address_space(3))) void*)l,
        16, 0, 0);
}

// ---------------------------------------------------------------------------
// prep: blocks [0,4096) convert x fp32->bf16; blocks [4096,8192) build W_eff.
// ---------------------------------------------------------------------------
__global__ void prep_kernel(const float* __restrict__ x, u16* __restrict__ xb,
                            const float* __restrict__ wr, const float* __restrict__ wi,
                            const float* __restrict__ wj, const float* __restrict__ wk,
                            u16* __restrict__ wb) {
    const int b = blockIdx.x;
    if (b < 4096) {
        const int n4 = (QM * QK) / 4;
        for (int i = b * blockDim.x + threadIdx.x; i < n4; i += 4096 * blockDim.x) {
            float4 v = reinterpret_cast<const float4*>(x)[i];
            ushort4 o;
            o.x = f2bf(v.x); o.y = f2bf(v.y); o.z = f2bf(v.z); o.w = f2bf(v.w);
            reinterpret_cast<ushort4*>(xb)[i] = o;
        }
    } else {
        int i = (b - 4096) * blockDim.x + threadIdx.x;   // [0, QN*QK/4)
        int n = i >> 9;
        int p = i & 511;
        int q = n >> 2, co = n & 3;
        int base = (q << 9) + p;
        float r  = wr[base], ii = wi[base], jj = wj[base], kk = wk[base];
        float e0, e1, e2, e3;
        if      (co == 0) { e0 = r;  e1 = -ii; e2 = -jj; e3 = -kk; }
        else if (co == 1) { e0 = ii; e1 = r;   e2 = -jj; e3 = kk;  }
        else if (co == 2) { e0 = jj; e1 = ii;  e2 = r;   e3 = -kk; }
        else              { e0 = kk; e1 = -ii; e2 = jj;  e3 = r;   }
        ushort4 o;
        o.x = f2bf(e0); o.y = f2bf(e1); o.z = f2bf(e2); o.w = f2bf(e3);
        reinterpret_cast<ushort4*>(wb)[(n << 9) + p] = o;
    }
}

// ---------------------------------------------------------------------------
// LDS (u16): A bufs [0,16384) = 2 x 8192; B bufs [16384,40960) = 3 x 8192.
// Buf = 128 rows x 64 cols (16KB); physical 16B-chunk (r,cp) holds logical
// (r, cp ^ (r&7)) [involution, 0-conflict 16x16 read pattern].
// Per K-tile t: read A-buf t&1, B-buf t%3; stage A(t+1)->(t+1)&1 (pos 0/1),
// B(t+2)->(t+2)%3 (pos 2/3). END sync: lgkm(0)+vmcnt(4)+barrier.
// Race proof (= R13):
//   [1] A(t+1) dest buf^1: tile-(t-1) readers drained at t-1's END lgkm(0);
//       residency for t+1 via END vmcnt(4).
//   [2] B(t+2) dest (t+2)%3 disjoint from read buf t%3 and (t+1)%3;
//       buf t%3 next written at t+1 (B(t+3)), after my reads drained.
//   [3] END queue = [B(t+1)x4, A(t+1)x4, B(t+2)x4]; vmcnt(4) => tile t+1
//       fully resident, B(t+2) stays in flight.
//   [4] post-barrier pre-read targets resident bufs whose next writers run
//       after t+1's END barrier; my reads drain at t+1's END lgkm(0).
// Staging: half-tile = 64 rows x 8 chunks = 512 chunks; thread covers
// chunks {tid, 256+tid}: row = o*32 + (tid>>3), col = (tid&7)^(row&7)
// (row&7 is o-invariant since 32 % 8 == 0 -> one precomputed XOR col).
// ---------------------------------------------------------------------------
__global__ __launch_bounds__(256, 2) void qgemm_kernel(const u16* __restrict__ A,
                                                       const u16* __restrict__ B,
                                                       const float* __restrict__ bias,
                                                       float* __restrict__ C) {
    __shared__ __align__(16) u16 L[40960];      // 80 KB -> 2 blocks/CU

    const int bid = blockIdx.x;                 // 2048 blocks, %8==0
    const int swz = (bid & 7) * 256 + (bid >> 3);
    const int bm = swz >> 4;                    // 0..127
    const int bn = swz & 15;                    // 0..15

    const int tid = threadIdx.x;
    const int wid = tid >> 6, lane = tid & 63;
    const int wm = wid >> 1, wn = wid & 1;      // 2x2 wave grid
    const int lr = lane & 15, lg = lane >> 4;

    const u16* Asrc = A + (size_t)bm * 128 * QK;
    const u16* Bsrc = B + (size_t)bn * 128 * QK;

    const int rbase = tid >> 3;                      // 0..31
    const int clA = ((tid & 7) ^ (rbase & 7)) << 3;  // pre-swizzled global col

    f32x4 acc[4][4];
#pragma unroll
    for (int i = 0; i < 4; ++i)
#pragma unroll
        for (int j = 0; j < 4; ++j)
            acc[i][j] = (f32x4){0.f, 0.f, 0.f, 0.f};

    // stage one 64-row half (h) of a 128x64 tile: 2 async per thread
    auto stage = [&](const u16* src, int lbase, int k0) {
#pragma unroll
        for (int o = 0; o < 2; ++o)
            async_copy16(src + (size_t)(o * 32 + rbase) * QK + k0 + clA,
                         &L[lbase + o * 2048 + wid * 512]);
    };

    auto rdA = [&](const u16* LA, int mf, int ks) -> bf16x8 {
        const int r = wm * 64 + mf * 16 + lr;
        const int c = ((ks * 4 + lg) ^ (r & 7)) << 3;
        return *(const bf16x8*)&LA[r * 64 + c];
    };
    auto rdB = [&](const u16* LB, int nf, int ks) -> bf16x8 {
        const int r = wn * 64 + nf * 16 + lr;
        const int c = ((ks * 4 + lg) ^ (r & 7)) << 3;
        return *(const bf16x8*)&LB[r * 64 + c];
    };

    // carried across tiles: current tile's c0 operands (mf0,1 x nf0-3, ks0)
    bf16x8 a0[2], b0[4];

    // ab=t&1, bt=t%3, bt2=(t+2)%3, abn=(t+1)&1, btn=(t+1)%3 — all LITERAL.
    auto doTile = [&](const int ab, const int bt, const int bt2,
                      const int abn, const int btn, const int t,
                      const bool preRead) __attribute__((always_inline)) {
        const u16* LA  = &L[ab * 8192];
        const u16* LB  = &L[16384 + bt * 8192];
        const u16* LAn = &L[abn * 8192];
        const u16* LBn = &L[16384 + btn * 8192];
        const int tw1 = (t + 1) & 31, tw2 = (t + 2) & 31;
        const int oA = abn * 8192;                // A(t+1) dest
        const int oB = 16384 + bt2 * 8192;        // B(t+2) dest

        bf16x8 a1[2], b1[4], a2[2], a3[2];

        // ---- c0: stage A(t+1)h0; read a1(mf2,3 ks0); MFMA mf0,1 ks0 ------
        stage(Asrc, oA, tw1 * 64);
#pragma unroll
        for (int mf = 0; mf < 2; ++mf) a1[mf] = rdA(LA, 2 + mf, 0);
#pragma unroll
        for (int mf = 0; mf < 2; ++mf)
#pragma unroll
            for (int nf = 0; nf < 4; ++nf)
                acc[mf][nf] = __builtin_amdgcn_mfma_f32_16x16x32_bf16(a0[mf], b0[nf], acc[mf][nf], 0, 0, 0);

        // ---- c1: stage A(t+1)h1; read b1(ks1), a2(mf0,1 ks1); MFMA mf2,3 ks0
        stage(Asrc + 64 * QK, oA + 4096, tw1 * 64);
#pragma unroll
        for (int nf = 0; nf < 4; ++nf) b1[nf] = rdB(LB, nf, 1);
#pragma unroll
        for (int mf = 0; mf < 2; ++mf) a2[mf] = rdA(LA, mf, 1);
#pragma unroll
        for (int mf = 0; mf < 2; ++mf)
#pragma unroll
            for (int nf = 0; nf < 4; ++nf)
                acc[2 + mf][nf] = __builtin_amdgcn_mfma_f32_16x16x32_bf16(a1[mf], b0[nf], acc[2 + mf][nf], 0, 0, 0);

        // ---- c2: stage B(t+2)h0; read a3(mf2,3 ks1); MFMA mf0,1 ks1 ------
        stage(Bsrc, oB, tw2 * 64);
#pragma unroll
        for (int mf = 0; mf < 2; ++mf) a3[mf] = rdA(LA, 2 + mf, 1);
#pragma unroll
        for (int mf = 0; mf < 2; ++mf)
#pragma unroll
            for (int nf = 0; nf < 4; ++nf)
                acc[mf][nf] = __builtin_amdgcn_mfma_f32_16x16x32_bf16(a2[mf], b1[nf], acc[mf][nf], 0, 0, 0);

        // ---- c3: stage B(t+2)h1; END sync; pre-read c0(t+1); MFMA mf2,3 ks1
        stage(Bsrc + 64 * QK, oB + 4096, tw2 * 64);
        asm volatile("s_waitcnt lgkmcnt(0) vmcnt(4)" ::: "memory");
        __builtin_amdgcn_s_barrier();
        if (preRead) {
#pragma unroll
            for (int nf = 0; nf < 4; ++nf) b0[nf] = rdB(LBn, nf, 0);
#pragma unroll
            for (int mf = 0; mf < 2; ++mf) a0[mf] = rdA(LAn, mf, 0);
        }
#pragma unroll
        for (int mf = 0; mf < 2; ++mf)
#pragma unroll
            for (int nf = 0; nf < 4; ++nf)
                acc[2 + mf][nf] = __builtin_amdgcn_mfma_f32_16x16x32_bf16(a3[mf], b1[nf], acc[2 + mf][nf], 0, 0, 0);
    };

    // prologue: A(0)->Abuf0, B(0)->Bbuf0, B(1)->Bbuf1
    stage(Asrc,           0,           0);
    stage(Asrc + 64 * QK, 4096,        0);
    stage(Bsrc,           16384,           0);
    stage(Bsrc + 64 * QK, 16384 + 4096,    0);
    stage(Bsrc,           16384 + 8192,        64);
    stage(Bsrc + 64 * QK, 16384 + 8192 + 4096, 64);
    asm volatile("s_waitcnt vmcnt(4)" ::: "memory");   // A(0),B(0) resident
    __builtin_amdgcn_s_barrier();
    // read tile 0's c0 operands
#pragma unroll
    for (int nf = 0; nf < 4; ++nf) b0[nf] = rdB(&L[16384], nf, 0);
#pragma unroll
    for (int mf = 0; mf < 2; ++mf) a0[mf] = rdA(&L[0], mf, 0);

    // 32 tiles = 5 x 6 (lcm of rings 2,3) + 2 tail; literal ring indices.
    //            ab bt bt2 abn btn  t
    for (int t = 0; t < 30; t += 6) {
        doTile(0, 0, 2, 1, 1, t,     true);
        doTile(1, 1, 0, 0, 2, t + 1, true);
        doTile(0, 2, 1, 1, 0, t + 2, true);
        doTile(1, 0, 2, 0, 1, t + 3, true);
        doTile(0, 1, 0, 1, 2, t + 4, true);
        doTile(1, 2, 1, 0, 0, t + 5, true);
    }
    doTile(0, 0, 2, 1, 1, 30, true);
    doTile(1, 1, 0, 0, 2, 31, false);   // last tile: no wrap pre-read

    // epilogue: C/D layout col = lane&15, row = (lane>>4)*4 + reg
    const int colbase = bn * 128 + wn * 64;
    const int rowbase = bm * 128 + wm * 64;
    float bsv[4];
#pragma unroll
    for (int nf = 0; nf < 4; ++nf) bsv[nf] = bias[colbase + nf * 16 + lr];
    float* Cb = C + (size_t)rowbase * QN + colbase;
#pragma unroll
    for (int mf = 0; mf < 4; ++mf)
#pragma unroll
        for (int nf = 0; nf < 4; ++nf)
#pragma unroll
            for (int v = 0; v < 4; ++v)
                Cb[(size_t)(mf * 16 + lg * 4 + v) * QN + nf * 16 + lr] = acc[mf][nf][v] + bsv[nf];
}

// ---------------------------------------------------------------------------
extern "C" void kernel_launch(void* const* d_in, const int* in_sizes, int n_in,
                              void* d_out, int out_size, void* d_ws, size_t ws_size,
                              hipStream_t stream) {
    const float* x    = (const float*)d_in[0];
    const float* wr   = (const float*)d_in[1];
    const float* wi   = (const float*)d_in[2];
    const float* wj   = (const float*)d_in[3];
    const float* wk   = (const float*)d_in[4];
    const float* bias = (const float*)d_in[5];
    float* out = (float*)d_out;

    u16* xb = (u16*)d_ws;                                   // 64 MB
    u16* wb = (u16*)((char*)d_ws + (size_t)QM * QK * 2);    // 8 MB

    prep_kernel<<<8192, 256, 0, stream>>>(x, xb, wr, wi, wj, wk, wb);
    qgemm_kernel<<<2048, 256, 0, stream>>>(xb, wb, bias, out);
}

// Round 18
// 153.861 us; speedup vs baseline: 1.5617x; 1.1142x over previous
//
#include <hip/hip_runtime.h>

// ---------------------------------------------------------------------------
// QuaternionLinear == one dense GEMM: out[M,N] = x[M,K] @ W_eff[N,K]^T + bias
//   M = 16384 (B*S), N = 2048 (OUT_F), K = 2048 (IN_F)
// Pipeline: prep (fp32->bf16 x + build W_eff) ; qgemm.
// FINAL = R13 (session best, 153.9us): one-cluster operand lookahead,
// A 2-ring + B 3-ring LDS (160KB), chunk-XOR swizzle (0 bank conflicts),
// ONE end-of-tile lgkm(0)+vmcnt(4)+barrier, literal ring indices, XCD
// swizzle, 16x16x32 MFMA, no setprio.
// Tile body: readsC0(carried) | stageA0 readsC1 MFMA0 | stageA1 readsC2
// MFMA1 | stageB0 readsC3 MFMA2 | stageB1 END-sync barrier readsC0' MFMA3
// Refuted alternatives (R5-R17): barrier-count variants (invariant),
// 16-wave block (R8), wave stagger (R9: acc spill), cvt fusion (R10),
// 32x32 MFMA (R11/R16: conflict-free LDS XOR coalesced HBM impossible with
// global_load_lds), ring rebalance (R12: B prefetch distance), instruction
// interleave (R14: neutral), setprio (R15: fences regress), 128 tile
// 2 blocks/CU (R17: 2.6x FETCH).
// ---------------------------------------------------------------------------

typedef unsigned short u16;
typedef __bf16 bf16x8 __attribute__((ext_vector_type(8)));
typedef float f32x4 __attribute__((ext_vector_type(4)));

#define QM 16384
#define QN 2048
#define QK 2048

__device__ __forceinline__ u16 f2bf(float f) {
    union { float f; unsigned u; } v;
    v.f = f;
    unsigned r = v.u + 0x7FFFu + ((v.u >> 16) & 1u);
    return (u16)(r >> 16);
}

__device__ __forceinline__ void async_copy16(const u16* g, u16* l) {
    __builtin_amdgcn_global_load_lds(
        (const __attribute__((address_space(1))) void*)g,
        (__attribute__((address_space(3))) void*)l,
        16, 0, 0);
}

// ---------------------------------------------------------------------------
// prep: blocks [0,4096) convert x fp32->bf16; blocks [4096,8192) build W_eff.
// ---------------------------------------------------------------------------
__global__ void prep_kernel(const float* __restrict__ x, u16* __restrict__ xb,
                            const float* __restrict__ wr, const float* __restrict__ wi,
                            const float* __restrict__ wj, const float* __restrict__ wk,
                            u16* __restrict__ wb) {
    const int b = blockIdx.x;
    if (b < 4096) {
        const int n4 = (QM * QK) / 4;
        for (int i = b * blockDim.x + threadIdx.x; i < n4; i += 4096 * blockDim.x) {
            float4 v = reinterpret_cast<const float4*>(x)[i];
            ushort4 o;
            o.x = f2bf(v.x); o.y = f2bf(v.y); o.z = f2bf(v.z); o.w = f2bf(v.w);
            reinterpret_cast<ushort4*>(xb)[i] = o;
        }
    } else {
        int i = (b - 4096) * blockDim.x + threadIdx.x;   // [0, QN*QK/4)
        int n = i >> 9;
        int p = i & 511;
        int q = n >> 2, co = n & 3;
        int base = (q << 9) + p;
        float r  = wr[base], ii = wi[base], jj = wj[base], kk = wk[base];
        float e0, e1, e2, e3;
        if      (co == 0) { e0 = r;  e1 = -ii; e2 = -jj; e3 = -kk; }
        else if (co == 1) { e0 = ii; e1 = r;   e2 = -jj; e3 = kk;  }
        else if (co == 2) { e0 = jj; e1 = ii;  e2 = r;   e3 = -kk; }
        else              { e0 = kk; e1 = -ii; e2 = jj;  e3 = r;   }
        ushort4 o;
        o.x = f2bf(e0); o.y = f2bf(e1); o.z = f2bf(e2); o.w = f2bf(e3);
        reinterpret_cast<ushort4*>(wb)[(n << 9) + p] = o;
    }
}

// ---------------------------------------------------------------------------
// LDS (u16): A bufs [0,32768) = 2 x 16384; B bufs [32768,81920) = 3 x 16384.
// Buf = 256 rows x 64 cols; physical 16B-chunk (r,cp) holds logical
// (r, cp ^ (r&7)) [involution, verified 0-conflict 16x16 read pattern].
// Per K-tile t: read A-buf t&1, B-buf t%3; stage A(t+1)->(t+1)&1 (pos 0/1),
// B(t+2)->(t+2)%3 (pos 2/3). END sync: lgkm(0)+vmcnt(4)+barrier.
// Race proof:
//   [1] A(t+1) dest buf^1: tile-(t-1) readers drained at t-1's END lgkm(0);
//       residency for t+1 via END vmcnt(4).
//   [2] B(t+2) dest (t+2)%3 disjoint from read buf t%3 and (t+1)%3;
//       buf t%3 next written at t+1 (B(t+3)), after my reads drained.
//   [3] END queue = [B(t+1)x4, A(t+1)x4, B(t+2)x4]; vmcnt(4) => tile t+1
//       fully resident, B(t+2) stays in flight.
//   [4] post-barrier readsC0(t+1): A-buf (t+1)&1 resident per [3]+barrier;
//       B-buf (t+1)%3 resident since t-1; their next writers execute after
//       t+1's END barrier, my reads drain at t+1's END lgkm(0).
// ---------------------------------------------------------------------------
__global__ __launch_bounds__(512, 2) void qgemm_kernel(const u16* __restrict__ A,
                                                       const u16* __restrict__ B,
                                                       const float* __restrict__ bias,
                                                       float* __restrict__ C) {
    __shared__ __align__(16) u16 L[81920];      // 160 KB

    const int bid = blockIdx.x;                 // 512 blocks, %8==0
    const int swz = (bid & 7) * 64 + (bid >> 3);
    const int bm = swz >> 3;                    // 0..63
    const int bn = swz & 7;                     // 0..7

    const int tid = threadIdx.x;
    const int wid = tid >> 6, lane = tid & 63;
    const int wm = wid >> 2, wn = wid & 3;
    const int lr = lane & 15, lg = lane >> 4;

    const u16* Asrc = A + (size_t)bm * 256 * QK;
    const u16* Bsrc = B + (size_t)bn * 256 * QK;

    // staging: half-tile = 128 rows x 64 cols; thread covers rows {rA, rA+64}
    const int rA  = tid >> 3;                        // 0..63
    const int clA = ((tid & 7) ^ (rA & 7)) << 3;     // pre-swizzled global col
    const size_t soff = (size_t)rA * QK + clA;

    f32x4 acc[8][4];
#pragma unroll
    for (int i = 0; i < 8; ++i)
#pragma unroll
        for (int j = 0; j < 4; ++j)
            acc[i][j] = (f32x4){0.f, 0.f, 0.f, 0.f};

    auto stage = [&](const u16* src, int lbase, int k0) {
#pragma unroll
        for (int o = 0; o < 2; ++o)
            async_copy16(src + (size_t)(o * 64) * QK + k0 + soff,
                         &L[lbase + o * 4096 + wid * 512]);
    };

    auto rdA = [&](const u16* LA, int mf, int ks) -> bf16x8 {
        const int r = wm * 128 + mf * 16 + lr;
        const int c = ((ks * 4 + lg) ^ (r & 7)) << 3;
        return *(const bf16x8*)&LA[r * 64 + c];
    };
    auto rdB = [&](const u16* LB, int nf, int ks) -> bf16x8 {
        const int r = wn * 64 + nf * 16 + lr;
        const int c = ((ks * 4 + lg) ^ (r & 7)) << 3;
        return *(const bf16x8*)&LB[r * 64 + c];
    };

    // carried across the loop: current tile's c0 operands (read after the
    // previous tile's END barrier).
    bf16x8 a0[4], b0[4];

    // ab=t&1, bt=t%3, bt2=(t+2)%3, abn=(t+1)&1, btn=(t+1)%3 — all LITERAL.
    auto doTile = [&](const int ab, const int bt, const int bt2,
                      const int abn, const int btn, const int t,
                      const bool preRead) __attribute__((always_inline)) {
        const u16* LA  = &L[ab * 16384];
        const u16* LB  = &L[32768 + bt * 16384];
        const u16* LAn = &L[abn * 16384];
        const u16* LBn = &L[32768 + btn * 16384];
        const int tw1 = (t + 1) & 31, tw2 = (t + 2) & 31;
        const int oA = abn * 16384;               // A(t+1) dest
        const int oB = 32768 + bt2 * 16384;       // B(t+2) dest

        bf16x8 a1[4], b1[4], a2[4], a3[4];

        // ---- stage A(t+1)h0; readsC1; MFMA c0 (a0,b0 carried) ------------
        stage(Asrc, oA, tw1 * 64);
#pragma unroll
        for (int mf = 0; mf < 4; ++mf) a1[mf] = rdA(LA, 4 + mf, 0);
#pragma unroll
        for (int mf = 0; mf < 4; ++mf)
#pragma unroll
            for (int nf = 0; nf < 4; ++nf)
                acc[mf][nf] = __builtin_amdgcn_mfma_f32_16x16x32_bf16(a0[mf], b0[nf], acc[mf][nf], 0, 0, 0);

        // ---- stage A(t+1)h1; readsC2; MFMA c1 -----------------------------
        stage(Asrc + 128 * QK, oA + 8192, tw1 * 64);
#pragma unroll
        for (int nf = 0; nf < 4; ++nf) b1[nf] = rdB(LB, nf, 1);
#pragma unroll
        for (int mf = 0; mf < 4; ++mf) a2[mf] = rdA(LA, mf, 1);
#pragma unroll
        for (int mf = 0; mf < 4; ++mf)
#pragma unroll
            for (int nf = 0; nf < 4; ++nf)
                acc[4 + mf][nf] = __builtin_amdgcn_mfma_f32_16x16x32_bf16(a1[mf], b0[nf], acc[4 + mf][nf], 0, 0, 0);

        // ---- stage B(t+2)h0; readsC3; MFMA c2 -----------------------------
        stage(Bsrc, oB, tw2 * 64);
#pragma unroll
        for (int mf = 0; mf < 4; ++mf) a3[mf] = rdA(LA, 4 + mf, 1);
#pragma unroll
        for (int mf = 0; mf < 4; ++mf)
#pragma unroll
            for (int nf = 0; nf < 4; ++nf)
                acc[mf][nf] = __builtin_amdgcn_mfma_f32_16x16x32_bf16(a2[mf], b1[nf], acc[mf][nf], 0, 0, 0);

        // ---- stage B(t+2)h1; END sync; readsC0(t+1); MFMA c3 --------------
        stage(Bsrc + 128 * QK, oB + 8192, tw2 * 64);
        asm volatile("s_waitcnt lgkmcnt(0) vmcnt(4)" ::: "memory");
        __builtin_amdgcn_s_barrier();
        if (preRead) {
#pragma unroll
            for (int nf = 0; nf < 4; ++nf) b0[nf] = rdB(LBn, nf, 0);
#pragma unroll
            for (int mf = 0; mf < 4; ++mf) a0[mf] = rdA(LAn, mf, 0);
        }
#pragma unroll
        for (int mf = 0; mf < 4; ++mf)
#pragma unroll
            for (int nf = 0; nf < 4; ++nf)
                acc[4 + mf][nf] = __builtin_amdgcn_mfma_f32_16x16x32_bf16(a3[mf], b1[nf], acc[4 + mf][nf], 0, 0, 0);
    };

    // prologue: A(0)->Abuf0, B(0)->Bbuf0, B(1)->Bbuf1
    stage(Asrc,            0,             0);
    stage(Asrc + 128 * QK, 8192,          0);
    stage(Bsrc,            32768,             0);
    stage(Bsrc + 128 * QK, 32768 + 8192,      0);
    stage(Bsrc,            32768 + 16384,        64);
    stage(Bsrc + 128 * QK, 32768 + 16384 + 8192, 64);
    asm volatile("s_waitcnt vmcnt(4)" ::: "memory");   // A(0),B(0) resident
    __builtin_amdgcn_s_barrier();
    // read tile 0's c0 operands
#pragma unroll
    for (int nf = 0; nf < 4; ++nf) b0[nf] = rdB(&L[32768], nf, 0);
#pragma unroll
    for (int mf = 0; mf < 4; ++mf) a0[mf] = rdA(&L[0], mf, 0);

    // 32 tiles = 5 x 6 (lcm of rings 2,3) + 2 tail; literal ring indices.
    //            ab bt bt2 abn btn  t
    for (int t = 0; t < 30; t += 6) {
        doTile(0, 0, 2, 1, 1, t,     true);
        doTile(1, 1, 0, 0, 2, t + 1, true);
        doTile(0, 2, 1, 1, 0, t + 2, true);
        doTile(1, 0, 2, 0, 1, t + 3, true);
        doTile(0, 1, 0, 1, 2, t + 4, true);
        doTile(1, 2, 1, 0, 0, t + 5, true);
    }
    doTile(0, 0, 2, 1, 1, 30, true);
    doTile(1, 1, 0, 0, 2, 31, false);   // last tile: no wrap pre-read

    // epilogue: C/D layout col = lane&15, row = (lane>>4)*4 + reg
    const int colbase = bn * 256 + wn * 64;
    const int rowbase = bm * 256 + wm * 128;
    float bsv[4];
#pragma unroll
    for (int nf = 0; nf < 4; ++nf) bsv[nf] = bias[colbase + nf * 16 + lr];
    float* Cb = C + (size_t)rowbase * QN + colbase;
#pragma unroll
    for (int mf = 0; mf < 8; ++mf)
#pragma unroll
        for (int nf = 0; nf < 4; ++nf)
#pragma unroll
            for (int v = 0; v < 4; ++v)
                Cb[(size_t)(mf * 16 + lg * 4 + v) * QN + nf * 16 + lr] = acc[mf][nf][v] + bsv[nf];
}

// ---------------------------------------------------------------------------
extern "C" void kernel_launch(void* const* d_in, const int* in_sizes, int n_in,
                              void* d_out, int out_size, void* d_ws, size_t ws_size,
                              hipStream_t stream) {
    const float* x    = (const float*)d_in[0];
    const float* wr   = (const float*)d_in[1];
    const float* wi   = (const float*)d_in[2];
    const float* wj   = (const float*)d_in[3];
    const float* wk   = (const float*)d_in[4];
    const float* bias = (const float*)d_in[5];
    float* out = (float*)d_out;

    u16* xb = (u16*)d_ws;                                   // 64 MB
    u16* wb = (u16*)((char*)d_ws + (size_t)QM * QK * 2);    // 8 MB

    prep_kernel<<<8192, 256, 0, stream>>>(x, xb, wr, wi, wj, wk, wb);
    qgemm_kernel<<<512, 512, 0, stream>>>(xb, wb, bias, out);
}